// Round 4
// baseline (733.360 us; speedup 1.0000x reference)
//
#include <hip/hip_runtime.h>
#include <hip/hip_bf16.h>

// 9x9 VALID conv, 4096x4096 f32 -> 4088x4088 f32, + scalar bias.
// Sliding-row design, no LDS: each thread owns an 8-row x 4-col output strip
// and scans 16 input rows; each loaded row (3x float4) feeds up to 9 resident
// accumulator rows. 1.5 loads/output. Taps uniform -> SGPR. No barriers.

#define H 4096
#define W 4096
#define OH 4088
#define OW 4088
#define ROWS 8              // output rows per thread
#define IN_ROWS (ROWS + 8)  // 16 input rows scanned

__global__ __launch_bounds__(256, 4)
void conv9x9_kernel(const float* __restrict__ X,
                    const float* __restrict__ K,
                    const float* __restrict__ B,
                    float* __restrict__ out) {
    const int tid = threadIdx.x;
    const int tx = tid & 63;        // 64 lanes across columns
    const int ty = tid >> 6;        // 4 waves stacked vertically
    const int bx = blockIdx.x;      // 16 col-tiles of 256
    const int by = blockIdx.y;      // 128 row-tiles of 32

    const int r0 = by * 32 + ty * ROWS;   // first output row of this thread
    const int c0 = bx * 256 + tx * 4;     // first output col of this thread

    // clamped column bases (row-independent; identity for interior threads;
    // clamped lanes only produce outputs that are masked at store time)
    int gc[3];
#pragma unroll
    for (int q = 0; q < 3; ++q) {
        int g = c0 + 4 * q;
        gc[q] = (g > W - 4) ? (W - 4) : g;
    }

    const float bias = B[0];
    float acc[ROWS][4];
#pragma unroll
    for (int i = 0; i < ROWS; ++i)
#pragma unroll
        for (int j = 0; j < 4; ++j)
            acc[i][j] = bias;

#pragma unroll
    for (int t = 0; t < IN_ROWS; ++t) {
        int gr = r0 + t;
        if (gr > H - 1) gr = H - 1;   // clamped rows only feed masked outputs
        const float* rowp = X + (size_t)gr * W;

        float seg[12];
#pragma unroll
        for (int q = 0; q < 3; ++q) {
            float4 v = *(const float4*)(rowp + gc[q]);
            seg[q * 4 + 0] = v.x; seg[q * 4 + 1] = v.y;
            seg[q * 4 + 2] = v.z; seg[q * 4 + 3] = v.w;
        }

        // input row t contributes to output rows i = t-8 .. t (kr = t-i)
#pragma unroll
        for (int i = 0; i < ROWS; ++i) {
            const int kr = t - i;
            if (kr < 0 || kr > 8) continue;   // compile-time pruned
#pragma unroll
            for (int kc = 0; kc < 9; ++kc) {
                const float kv = K[kr * 9 + kc];   // uniform -> SGPR
#pragma unroll
                for (int j = 0; j < 4; ++j)
                    acc[i][j] = fmaf(kv, seg[kc + j], acc[i][j]);
            }
        }
    }

    // store: per wave-row 64 lanes x float4 = 1KB contiguous.
    // c0 < OW implies the whole float4 is in-bounds (OW % 4 == 0).
    if (c0 < OW) {
#pragma unroll
        for (int i = 0; i < ROWS; ++i) {
            const int orow = r0 + i;
            if (orow < OH) {
                float4 v = { acc[i][0], acc[i][1], acc[i][2], acc[i][3] };
                *(float4*)(out + (size_t)orow * OW + c0) = v;
            }
        }
    }
}

extern "C" void kernel_launch(void* const* d_in, const int* in_sizes, int n_in,
                              void* d_out, int out_size, void* d_ws, size_t ws_size,
                              hipStream_t stream) {
    const float* X = (const float*)d_in[0];
    const float* K = (const float*)d_in[1];
    const float* B = (const float*)d_in[2];
    float* out = (float*)d_out;

    dim3 grid(W / 256, (OH + 31) / 32);   // 16 x 128 blocks
    dim3 block(256);
    conv9x9_kernel<<<grid, block, 0, stream>>>(X, K, B, out);
}

// Round 5
// 651.152 us; speedup vs baseline: 1.1263x; 1.1263x over previous
//
#include <hip/hip_runtime.h>
#include <hip/hip_bf16.h>

// 9x9 VALID conv, 4096x4096 f32 -> 4088x4088 f32, + scalar bias.
// No-LDS, latency-tolerant design: each thread owns a 4-row x 8-col output
// tile. 12-row sliding window with explicit one-row-ahead prefetch: per row,
// 4 float4 loads (issued early) feed 288 FMAs. acc 32 + 1 row buffer keeps
// VGPR ~80 (round 4's 16-row window spilled to scratch: 2.3 GB traffic).

#define H 4096
#define W 4096
#define OH 4088
#define OW 4088

__global__ __launch_bounds__(256, 4)
void conv9x9_kernel(const float* __restrict__ X,
                    const float* __restrict__ K,
                    const float* __restrict__ B,
                    float* __restrict__ out) {
    const int tid = threadIdx.x;
    const int tx = tid & 63;        // 64 lanes across columns (8 cols each)
    const int ty = tid >> 6;        // 4 waves stacked vertically (4 rows each)
    const int bx = blockIdx.x;      // 8 col-tiles of 512
    const int by = blockIdx.y;      // 256 row-tiles of 16

    const int r0 = by * 16 + ty * 4;    // first output row of this thread
    const int c0 = bx * 512 + tx * 8;   // first output col of this thread

    // clamped float4 column bases (identity for in-bounds lanes; clamped
    // lanes only produce outputs that are masked at store time)
    int gc[4];
#pragma unroll
    for (int q = 0; q < 4; ++q) {
        int g = c0 + 4 * q;
        gc[q] = (g > W - 4) ? (W - 4) : g;
    }

    const float bias = B[0];
    float acc[4][8];
#pragma unroll
    for (int i = 0; i < 4; ++i)
#pragma unroll
        for (int j = 0; j < 8; ++j)
            acc[i][j] = bias;

    // prefetch row 0 (r0 <= 4092 < H, no clamp needed)
    float4 nxt[4];
    {
        const float* rowp = X + (size_t)r0 * W;
#pragma unroll
        for (int q = 0; q < 4; ++q)
            nxt[q] = *(const float4*)(rowp + gc[q]);
    }

#pragma unroll
    for (int t = 0; t < 12; ++t) {
        // consume prefetched row into seg (register renames, not real moves)
        float seg[16];
#pragma unroll
        for (int q = 0; q < 4; ++q) {
            seg[q * 4 + 0] = nxt[q].x; seg[q * 4 + 1] = nxt[q].y;
            seg[q * 4 + 2] = nxt[q].z; seg[q * 4 + 3] = nxt[q].w;
        }

        // issue next row's loads BEFORE this row's FMA block
        if (t < 11) {
            int gr = r0 + t + 1;
            if (gr > H - 1) gr = H - 1;   // clamped rows only feed masked rows
            const float* rowp = X + (size_t)gr * W;
#pragma unroll
            for (int q = 0; q < 4; ++q)
                nxt[q] = *(const float4*)(rowp + gc[q]);
        }

        // input row t contributes to output rows i = t-8 .. t  (kr = t-i)
#pragma unroll
        for (int kr = 0; kr < 9; ++kr) {
            const int i = t - kr;
            if (i < 0 || i > 3) continue;    // compile-time pruned
#pragma unroll
            for (int kc = 0; kc < 9; ++kc) {
                const float kv = K[kr * 9 + kc];   // uniform -> SGPR
#pragma unroll
                for (int j = 0; j < 8; ++j)
                    acc[i][j] = fmaf(kv, seg[kc + j], acc[i][j]);
            }
        }
    }

    // store: 8 contiguous floats per lane-row; OW % 8 == 0 -> all-or-nothing
    if (c0 < OW) {
#pragma unroll
        for (int i = 0; i < 4; ++i) {
            const int orow = r0 + i;
            if (orow < OH) {
                float4 v0 = { acc[i][0], acc[i][1], acc[i][2], acc[i][3] };
                float4 v1 = { acc[i][4], acc[i][5], acc[i][6], acc[i][7] };
                float* p = out + (size_t)orow * OW + c0;
                *(float4*)p = v0;
                *(float4*)(p + 4) = v1;
            }
        }
    }
}

extern "C" void kernel_launch(void* const* d_in, const int* in_sizes, int n_in,
                              void* d_out, int out_size, void* d_ws, size_t ws_size,
                              hipStream_t stream) {
    const float* X = (const float*)d_in[0];
    const float* K = (const float*)d_in[1];
    const float* B = (const float*)d_in[2];
    float* out = (float*)d_out;

    dim3 grid(W / 512, H / 16);   // 8 x 256 = 2048 blocks (8 per CU)
    dim3 block(256);
    conv9x9_kernel<<<grid, block, 0, stream>>>(X, K, B, out);
}

// Round 6
// 181.742 us; speedup vs baseline: 4.0352x; 3.5828x over previous
//
#include <hip/hip_runtime.h>
#include <hip/hip_bf16.h>

// 9x9 VALID conv, 4096x4096 f32 -> 4088x4088 f32, + scalar bias.
// No-LDS, latency-tolerant: each thread owns a 4-row x 8-col output tile.
// 12-row sliding window, one-row-ahead prefetch: per row, 4 float4 loads
// (issued before the FMA block) feed 288 FMAs. 1.5 loads/output.
//
// NOTE on launch bounds: __launch_bounds__(256,4) capped the RA at 64 VGPR
// (observed rounds 4/5) and spilled ~1.6KB/thread of accumulator state ->
// 1.9 GB of scratch traffic. No min-waves clause: RA takes ~128, no spill.

#define H 4096
#define W 4096
#define OH 4088
#define OW 4088

__global__ __launch_bounds__(256)
void conv9x9_kernel(const float* __restrict__ X,
                    const float* __restrict__ K,
                    const float* __restrict__ B,
                    float* __restrict__ out) {
    const int tid = threadIdx.x;
    const int tx = tid & 63;        // 64 lanes across columns (8 cols each)
    const int ty = tid >> 6;        // 4 waves stacked vertically (4 rows each)
    const int bx = blockIdx.x;      // 8 col-tiles of 512
    const int by = blockIdx.y;      // 256 row-tiles of 16

    const int r0 = by * 16 + ty * 4;    // first output row of this thread
    const int c0 = bx * 512 + tx * 8;   // first output col of this thread

    // clamped float4 column bases (identity for in-bounds lanes; clamped
    // lanes only produce outputs that are masked at store time)
    int gc[4];
#pragma unroll
    for (int q = 0; q < 4; ++q) {
        int g = c0 + 4 * q;
        gc[q] = (g > W - 4) ? (W - 4) : g;
    }

    const float bias = B[0];
    float acc[4][8];
#pragma unroll
    for (int i = 0; i < 4; ++i)
#pragma unroll
        for (int j = 0; j < 8; ++j)
            acc[i][j] = bias;

    // prefetch row 0 (r0 <= 4092 < H, no clamp needed)
    float4 nxt[4];
    {
        const float* rowp = X + (size_t)r0 * W;
#pragma unroll
        for (int q = 0; q < 4; ++q)
            nxt[q] = *(const float4*)(rowp + gc[q]);
    }

#pragma unroll
    for (int t = 0; t < 12; ++t) {
        // consume prefetched row (register renames / cheap movs)
        float seg[16];
#pragma unroll
        for (int q = 0; q < 4; ++q) {
            seg[q * 4 + 0] = nxt[q].x; seg[q * 4 + 1] = nxt[q].y;
            seg[q * 4 + 2] = nxt[q].z; seg[q * 4 + 3] = nxt[q].w;
        }

        // issue next row's loads BEFORE this row's FMA block
        if (t < 11) {
            int gr = r0 + t + 1;
            if (gr > H - 1) gr = H - 1;   // clamped rows only feed masked rows
            const float* rowp = X + (size_t)gr * W;
#pragma unroll
            for (int q = 0; q < 4; ++q)
                nxt[q] = *(const float4*)(rowp + gc[q]);
        }

        // input row t contributes to output rows i = t-kr, kr in [0,8]
#pragma unroll
        for (int kr = 0; kr < 9; ++kr) {
            const int i = t - kr;
            if (i < 0 || i > 3) continue;    // compile-time pruned
#pragma unroll
            for (int kc = 0; kc < 9; ++kc) {
                const float kv = K[kr * 9 + kc];   // uniform -> SGPR
#pragma unroll
                for (int j = 0; j < 8; ++j)
                    acc[i][j] = fmaf(kv, seg[kc + j], acc[i][j]);
            }
        }
    }

    // store: 8 contiguous floats per lane-row; OW % 8 == 0 -> all-or-nothing
    if (c0 < OW) {
#pragma unroll
        for (int i = 0; i < 4; ++i) {
            const int orow = r0 + i;
            if (orow < OH) {
                float4 v0 = { acc[i][0], acc[i][1], acc[i][2], acc[i][3] };
                float4 v1 = { acc[i][4], acc[i][5], acc[i][6], acc[i][7] };
                float* p = out + (size_t)orow * OW + c0;
                *(float4*)p = v0;
                *(float4*)(p + 4) = v1;
            }
        }
    }
}

extern "C" void kernel_launch(void* const* d_in, const int* in_sizes, int n_in,
                              void* d_out, int out_size, void* d_ws, size_t ws_size,
                              hipStream_t stream) {
    const float* X = (const float*)d_in[0];
    const float* K = (const float*)d_in[1];
    const float* B = (const float*)d_in[2];
    float* out = (float*)d_out;

    dim3 grid(W / 512, H / 16);   // 8 x 256 = 2048 blocks (8 per CU)
    dim3 block(256);
    conv9x9_kernel<<<grid, block, 0, stream>>>(X, K, B, out);
}